// Round 11
// baseline (88.971 us; speedup 1.0000x reference)
//
#include <hip/hip_runtime.h>
#include <stdint.h>

// Shapes fixed by setup_inputs(): x [8192,512] f32, patterns [1024,512] f32,
// edges [7] f32. Outputs: [8192] argmax idx (as f32) ++ [8192] score (cnt/512).
//
// R11: MX-fp4 MFMA GEMM (R9-proven numerics). Pattern (A) one-hot fragments
// are PRE-EXPANDED in prep into the exact MFMA cell layout (2 MB, L2-resident)
// -- the hot loop just loads them. x rows (B) stay in-register expand4
// (cheap). 2D tile (R5 skeleton): 512 blocks, 128 pats x 128 rows, 4 accs,
// packed-key atomicMax epilogue. Cell (c16,j,h) holds dims c*16+h*8+j*4+t at
// reg t == byte-identical to R9's in-register A expansion => proven A/B
// operand symmetry (k-permutation invariance) preserved.
#define NROW 8192
#define NPAT 1024

typedef unsigned long long u64;
typedef unsigned int u32;
typedef unsigned char u8;
typedef __attribute__((ext_vector_type(4))) int i32x4;
typedef __attribute__((ext_vector_type(8))) int i32x8;
typedef __attribute__((ext_vector_type(16))) float f32x16;

__device__ __forceinline__ u32 bin7(float v, float e0, float e1, float e2,
                                    float e3, float e4, float e5, float e6) {
  return (u32)((v > e0) + (v > e1) + (v > e2) + (v > e3) + (v > e4) +
               (v > e5) + (v > e6));
}

// Quantize 16 consecutive dims -> 16 code bytes, PRE-SHIFTED (bin*4).
__device__ __forceinline__ int4 quant16n(const float4* s4, float e0, float e1,
                                         float e2, float e3, float e4,
                                         float e5, float e6) {
  int4 out;
  int* od = &out.x;
#pragma unroll
  for (int q = 0; q < 4; ++q) {
    float4 a = s4[q];
    od[q] = (int)((bin7(a.x, e0, e1, e2, e3, e4, e5, e6) << 2) |
                  ((bin7(a.y, e0, e1, e2, e3, e4, e5, e6) << 2) << 8) |
                  ((bin7(a.z, e0, e1, e2, e3, e4, e5, e6) << 2) << 16) |
                  ((bin7(a.w, e0, e1, e2, e3, e4, e5, e6) << 2) << 24));
  }
  return out;
}

// ---------------------------------------------------------------------------
// Prep (1152 blocks):
//  blocks [0,1024):   x -> byte-code cells xcode2[c16][h][row][8B] (R9
//                     verbatim; 8 dims per cell, pre-shifted bin*4).
//  blocks [1024,1152): patterns -> PRE-EXPANDED fp4 one-hot fragments
//                     pfrag[c16][j][h][pat][16B]: cell = dims
//                     c16*16 + h*8 + j*4 + t (t=reg 0..3), dword = 2<<(bin*4).
//                     Writes coalesced (consecutive pat). Zeroes best_packed.
// ---------------------------------------------------------------------------
__global__ __launch_bounds__(256) void prep_kernel(
    const float* __restrict__ x, const float* __restrict__ patterns,
    const float* __restrict__ edges, u8* __restrict__ xcode2,
    u8* __restrict__ pfrag, u32* __restrict__ best_packed) {
  const float e0 = edges[0], e1 = edges[1], e2 = edges[2], e3 = edges[3],
              e4 = edges[4], e5 = edges[5], e6 = edges[6];
  const int bid = blockIdx.x, tid = threadIdx.x;

  if (bid < 1024) {
    const int i = bid * 256 + tid;  // 0..262143
    const int row = i & 8191;
    const int c16 = i >> 13;
    const float4* s4 =
        reinterpret_cast<const float4*>(x + ((size_t)row << 9) + (c16 << 4));
    int4 cod = quant16n(s4, e0, e1, e2, e3, e4, e5, e6);
    const u64 lo = (u64)(u32)cod.x | ((u64)(u32)cod.y << 32);  // dims 0..7
    const u64 hi = (u64)(u32)cod.z | ((u64)(u32)cod.w << 32);  // dims 8..15
    *reinterpret_cast<u64*>(
        xcode2 + ((((size_t)c16 * 2 + 0) * 8192 + row) << 3)) = lo;
    *reinterpret_cast<u64*>(
        xcode2 + ((((size_t)c16 * 2 + 1) * 8192 + row) << 3)) = hi;
  } else {
    const int t = (bid - 1024) * 256 + tid;  // 0..32767
    const int c16 = t >> 10;
    const int pat = t & 1023;
    const float4* s4 = reinterpret_cast<const float4*>(
        patterns + ((size_t)pat << 9) + (c16 << 4));
    u32 oh[16];
#pragma unroll
    for (int q = 0; q < 4; ++q) {
      float4 a = s4[q];
      oh[q * 4 + 0] = 2u << (bin7(a.x, e0, e1, e2, e3, e4, e5, e6) << 2);
      oh[q * 4 + 1] = 2u << (bin7(a.y, e0, e1, e2, e3, e4, e5, e6) << 2);
      oh[q * 4 + 2] = 2u << (bin7(a.z, e0, e1, e2, e3, e4, e5, e6) << 2);
      oh[q * 4 + 3] = 2u << (bin7(a.w, e0, e1, e2, e3, e4, e5, e6) << 2);
    }
#pragma unroll
    for (int j = 0; j < 2; ++j) {
#pragma unroll
      for (int h2 = 0; h2 < 2; ++h2) {
        int4 cell;
        cell.x = (int)oh[h2 * 8 + j * 4 + 0];
        cell.y = (int)oh[h2 * 8 + j * 4 + 1];
        cell.z = (int)oh[h2 * 8 + j * 4 + 2];
        cell.w = (int)oh[h2 * 8 + j * 4 + 3];
        *reinterpret_cast<int4*>(
            pfrag + ((((size_t)(c16 * 4 + j * 2 + h2)) * 1024 + pat) << 4)) =
            cell;
      }
    }
    if (t < NROW) best_packed[t] = 0;
  }
}

// Expand 4 dims (pre-shifted codes bin*4 in the 4 bytes of w) into 4 dwords
// of fp4 one-hot nibbles (1.0 = 0x2 at nibble bin). B-side only now.
__device__ __forceinline__ i32x4 expand4(u32 w) {
  i32x4 f;
  f[0] = (int)(2u << (w & 0xFFu));
  f[1] = (int)(2u << ((w >> 8) & 0xFFu));
  f[2] = (int)(2u << ((w >> 16) & 0xFFu));
  f[3] = (int)(2u << (w >> 24));
  return f;
}

__device__ __forceinline__ i32x8 make8(i32x4 v) {
  i32x8 r;
  r[0] = v[0]; r[1] = v[1]; r[2] = v[2]; r[3] = v[3];
  r[4] = 0; r[5] = 0; r[6] = 0; r[7] = 0;  // fp4 uses operand regs 0-3
  return r;
}

#define MFMA_FP4(A, B, C)                                                \
  __builtin_amdgcn_mfma_scale_f32_32x32x64_f8f6f4(                       \
      (A), (B), (C), 4, 4, 0, 0x7F7F7F7F, 0, 0x7F7F7F7F)

// ---------------------------------------------------------------------------
// Match: fp4 MFMA GEMM D[pattern][row]. Block = 256 thr (4 waves), C-tile
// 128 pats x 128 rows; wave: pp = wid&1 (64-pat pair), rr = wid>>1 (64-row
// pair) -> 4 accs (dep distance 4). Per chunk (16 dims): 4 A-frag dwordx4
// loads (pre-expanded, zero VALU), 2 B-code u64 loads + 4 expand4, 8 MFMAs.
// Software prefetch of chunk c+1. Grid dim3(64,8) = 512 blocks = 2/CU.
// Epilogue: packed-key (cnt<<10)|(1023-p) atomicMax (first-index argmax).
// ---------------------------------------------------------------------------
__global__ __launch_bounds__(256, 2) void match_kernel(
    const u8* __restrict__ xcode2,  // [32][2][8192][8]
    const u8* __restrict__ pfrag,   // [32][2][2][1024][16]
    u32* __restrict__ best_packed) {
  const int tid = threadIdx.x;
  const int lane = tid & 63;
  const int h = lane >> 5;
  const int wid = tid >> 6;
  const int pp = wid & 1;
  const int rr = wid >> 1;
  const int rgb = blockIdx.x;  // 0..63 -> 128 rows
  const int pgb = blockIdx.y;  // 0..7  -> 128 patterns

  const int row0 = rgb * 128 + rr * 64 + (lane & 31);  // row1 = row0+32
  const int mA = pgb * 128 + pp * 64 + (lane & 31);    // pg1 = mA+32

  const u8* pR = xcode2 + (((size_t)h * 8192 + row0) << 3);
  const u8* pA = pfrag + (((size_t)h * 1024 + mA) << 4);
  // strides: pR chunk = 128KB; pA chunk = 64KB, j = 32KB, pg1 = +512B.

  f32x16 acc00 = {0};  // (pg0, row0)
  f32x16 acc10 = {0};  // (pg1, row0)
  f32x16 acc01 = {0};  // (pg0, row1)
  f32x16 acc11 = {0};  // (pg1, row1)

  u64 cR0 = *reinterpret_cast<const u64*>(pR);
  u64 cR1 = *reinterpret_cast<const u64*>(pR + 256);
  i32x4 a00 = *reinterpret_cast<const i32x4*>(pA);                // j0 pg0
  i32x4 a01 = *reinterpret_cast<const i32x4*>(pA + 512);          // j0 pg1
  i32x4 a10 = *reinterpret_cast<const i32x4*>(pA + 32768);        // j1 pg0
  i32x4 a11 = *reinterpret_cast<const i32x4*>(pA + 32768 + 512);  // j1 pg1

  for (int c = 0; c < 32; ++c) {
    u64 nR0, nR1;
    i32x4 n00, n01, n10, n11;
    if (c < 31) {
      const size_t ro = (size_t)(c + 1) << 17;
      const size_t ao = (size_t)(c + 1) << 16;
      nR0 = *reinterpret_cast<const u64*>(pR + ro);
      nR1 = *reinterpret_cast<const u64*>(pR + ro + 256);
      n00 = *reinterpret_cast<const i32x4*>(pA + ao);
      n01 = *reinterpret_cast<const i32x4*>(pA + ao + 512);
      n10 = *reinterpret_cast<const i32x4*>(pA + ao + 32768);
      n11 = *reinterpret_cast<const i32x4*>(pA + ao + 32768 + 512);
    }
    {  // j = 0
      const i32x8 A0 = make8(a00);
      const i32x8 A1 = make8(a01);
      const i32x8 b0 = make8(expand4((u32)cR0));
      const i32x8 b1 = make8(expand4((u32)cR1));
      acc00 = MFMA_FP4(A0, b0, acc00);
      acc10 = MFMA_FP4(A1, b0, acc10);
      acc01 = MFMA_FP4(A0, b1, acc01);
      acc11 = MFMA_FP4(A1, b1, acc11);
    }
    {  // j = 1
      const i32x8 A0 = make8(a10);
      const i32x8 A1 = make8(a11);
      const i32x8 b0 = make8(expand4((u32)(cR0 >> 32)));
      const i32x8 b1 = make8(expand4((u32)(cR1 >> 32)));
      acc00 = MFMA_FP4(A0, b0, acc00);
      acc10 = MFMA_FP4(A1, b0, acc10);
      acc01 = MFMA_FP4(A0, b1, acc01);
      acc11 = MFMA_FP4(A1, b1, acc11);
    }
    if (c < 31) {
      cR0 = nR0;
      cR1 = nR1;
      a00 = n00;
      a01 = n01;
      a10 = n10;
      a11 = n11;
    }
  }

  // Epilogue: C/D map col=lane&31 (this lane's row), pl=(r&3)+8*(r>>2)+4*h.
  const int pbase = pgb * 128 + pp * 64;
  u32 best0 = 0, best1 = 0;
#pragma unroll
  for (int r = 0; r < 16; ++r) {
    const int pl = (r & 3) + 8 * (r >> 2) + 4 * h;
    const u32 key0 = 1023u - (u32)(pbase + pl);
    const u32 key1 = 1023u - (u32)(pbase + 32 + pl);
    const u32 k00 = (((u32)acc00[r]) << 10) | key0;
    const u32 k10 = (((u32)acc10[r]) << 10) | key1;
    const u32 k01 = (((u32)acc01[r]) << 10) | key0;
    const u32 k11 = (((u32)acc11[r]) << 10) | key1;
    best0 = k00 > best0 ? k00 : best0;
    best0 = k10 > best0 ? k10 : best0;
    best1 = k01 > best1 ? k01 : best1;
    best1 = k11 > best1 ? k11 : best1;
  }
  atomicMax(&best_packed[row0], best0);
  atomicMax(&best_packed[row0 + 32], best1);
}

// ---------------------------------------------------------------------------
// Finalize: decode packed -> (index as float, score = cnt/512).
// ---------------------------------------------------------------------------
__global__ __launch_bounds__(256) void finalize_kernel(
    const u32* __restrict__ best_packed, float* __restrict__ out) {
  const int i = blockIdx.x * 256 + threadIdx.x;
  if (i >= NROW) return;
  const u32 v = best_packed[i];
  out[i] = (float)(1023u - (v & 1023u));
  out[NROW + i] = (float)(v >> 10) * (1.0f / 512.0f);
}

extern "C" void kernel_launch(void* const* d_in, const int* in_sizes, int n_in,
                              void* d_out, int out_size, void* d_ws,
                              size_t ws_size, hipStream_t stream) {
  const float* x = (const float*)d_in[0];         // [8192, 512]
  const float* patterns = (const float*)d_in[1];  // [1024, 512]
  const float* edges = (const float*)d_in[2];     // [7]
  float* out = (float*)d_out;                     // 16384 floats

  // Workspace: xcode2 4MB ++ pfrag 2MB ++ best_packed 32KB = 6.03MB.
  u8* xcode2 = (u8*)d_ws;                     // [32][2][8192][8]
  u8* pfrag = xcode2 + (size_t)64 * NROW * 8; // [32][2][2][1024][16]
  u32* best_packed = (u32*)(pfrag + (size_t)128 * NPAT * 16);

  prep_kernel<<<1152, 256, 0, stream>>>(x, patterns, edges, xcode2, pfrag,
                                        best_packed);
  match_kernel<<<dim3(64, 8), 256, 0, stream>>>(xcode2, pfrag, best_packed);
  finalize_kernel<<<NROW / 256, 256, 0, stream>>>(best_packed, out);
}